// Round 1
// baseline (991.334 us; speedup 1.0000x reference)
//
#include <hip/hip_runtime.h>
#include <hip/hip_bf16.h>

// LIF layer: Wx = x @ W^T  (x:[B,T,I] f32, W:[H,I] f32), then sequential scan
// over T:  u = al*(u - s) + (1-al)*wx ;  s = (u - 1 > 0) ? 1 : 0.
// Output: spikes [B,T,H] f32 (binary). Binary output means ANY spike flip is
// absmax=1.0 -> stay fp32 end-to-end this round.

#define ALPHA_LO_F ((float)0.8187307530779818)   // exp(-1/5)
#define ALPHA_HI_F ((float)0.9607894391523232)   // exp(-1/25)

// ---------------------------------------------------------------------------
// Kernel 1: fp32 "NT" GEMM  C[m,n] = sum_k A[m,k] * B[n,k]
// A = x flattened [M=B*T, K=I] row-major; B = W [N=H, K=I] row-major.
// Tile 64x64x16, 256 threads, 4x4 accumulator per thread.
// All dims divide tile sizes exactly for this problem (M=65536, N=512, K=512).
// ---------------------------------------------------------------------------
#define BM 64
#define BN 64
#define BK 16
__global__ __launch_bounds__(256) void gemm_nt_f32(
    const float* __restrict__ A,   // [M, K]
    const float* __restrict__ B,   // [N, K]
    float* __restrict__ C,         // [M, N]
    int M, int N, int K)
{
    __shared__ float As[BK][BM];   // stored transposed: As[k][m]
    __shared__ float Bs[BK][BN];   // Bs[k][n]

    const int tid = threadIdx.x;
    const int tm  = tid >> 4;          // 0..15 (output row group)
    const int tn  = tid & 15;          // 0..15 (output col group)
    const int m0  = blockIdx.y * BM;
    const int n0  = blockIdx.x * BN;

    // load mapping: each thread loads one float4 of the A tile and one of B
    const int lr = tid >> 2;           // 0..63 : tile row
    const int lk = (tid & 3) * 4;      // 0,4,8,12 : tile k offset

    float acc[4][4] = {};

    const float* Arow = A + (size_t)(m0 + lr) * K + lk;
    const float* Brow = B + (size_t)(n0 + lr) * K + lk;

    for (int k0 = 0; k0 < K; k0 += BK) {
        float4 av = *(const float4*)(Arow + k0);
        float4 bv = *(const float4*)(Brow + k0);
        As[lk + 0][lr] = av.x;  As[lk + 1][lr] = av.y;
        As[lk + 2][lr] = av.z;  As[lk + 3][lr] = av.w;
        Bs[lk + 0][lr] = bv.x;  Bs[lk + 1][lr] = bv.y;
        Bs[lk + 2][lr] = bv.z;  Bs[lk + 3][lr] = bv.w;
        __syncthreads();

        #pragma unroll
        for (int k = 0; k < BK; ++k) {
            float a[4], b[4];
            #pragma unroll
            for (int i = 0; i < 4; ++i) a[i] = As[k][tm * 4 + i];
            #pragma unroll
            for (int j = 0; j < 4; ++j) b[j] = Bs[k][tn * 4 + j];
            #pragma unroll
            for (int i = 0; i < 4; ++i)
                #pragma unroll
                for (int j = 0; j < 4; ++j)
                    acc[i][j] += a[i] * b[j];
        }
        __syncthreads();
    }

    #pragma unroll
    for (int i = 0; i < 4; ++i) {
        float4 v;
        v.x = acc[i][0]; v.y = acc[i][1]; v.z = acc[i][2]; v.w = acc[i][3];
        *(float4*)(C + (size_t)(m0 + tm * 4 + i) * N + n0 + tn * 4) = v;
    }
}

// ---------------------------------------------------------------------------
// Kernel 2: LIF scan. One thread per (b, h) sequence; T steps in order.
// Reads Wx in-place from `buf` and overwrites with the spike (read-before-
// write at the same index within the owning thread -> no hazard).
// ---------------------------------------------------------------------------
__global__ __launch_bounds__(256) void lif_scan(
    float* __restrict__ buf,            // [B, T, H]: in = Wx, out = spikes
    const float* __restrict__ alpha,    // [H]
    const float* __restrict__ u0,       // [B, H]
    const float* __restrict__ s0,       // [B, H]
    int B, int T, int H)
{
    const int h = blockIdx.x * blockDim.x + threadIdx.x;
    const int b = blockIdx.y;
    if (h >= H) return;

    float al = alpha[h];
    al = fminf(fmaxf(al, ALPHA_LO_F), ALPHA_HI_F);
    const float one_m_al = 1.0f - al;

    float u = u0[(size_t)b * H + h];
    float s = s0[(size_t)b * H + h];   // note: s0 is real-valued (uniform)

    size_t idx = (size_t)b * T * H + h;
    for (int t = 0; t < T; ++t, idx += H) {
        const float wx = buf[idx];
        u = al * (u - s) + one_m_al * wx;
        s = (u - 1.0f > 0.0f) ? 1.0f : 0.0f;
        buf[idx] = s;
    }
}

extern "C" void kernel_launch(void* const* d_in, const int* in_sizes, int n_in,
                              void* d_out, int out_size, void* d_ws, size_t ws_size,
                              hipStream_t stream) {
    const float* x     = (const float*)d_in[0];   // [B, T, I]
    const float* W     = (const float*)d_in[1];   // [H, I]
    const float* alpha = (const float*)d_in[2];   // [H]
    const float* u0    = (const float*)d_in[3];   // [B, H]
    const float* s0    = (const float*)d_in[4];   // [B, H]
    float* out = (float*)d_out;                   // [B, T, H]

    const int H = in_sizes[2];
    const int I = in_sizes[1] / H;
    const int B = in_sizes[3] / H;
    const int T = in_sizes[0] / (B * I);
    const int M = B * T;

    // 1) Wx -> d_out (exactly [B,T,H] f32; reused in-place by the scan)
    dim3 grid1(H / BN, M / BM);
    gemm_nt_f32<<<grid1, 256, 0, stream>>>(x, W, out, M, H, I);

    // 2) scan over T, in-place
    dim3 grid2((H + 255) / 256, B);
    lif_scan<<<grid2, 256, 0, stream>>>(out, alpha, u0, s0, B, T, H);
}

// Round 2
// 771.778 us; speedup vs baseline: 1.2845x; 1.2845x over previous
//
#include <hip/hip_runtime.h>
#include <hip/hip_bf16.h>

// LIF layer: Wx = x @ W^T  (x:[B,T,I] f32, W:[H,I] f32), then sequential scan
// over T:  u = al*(u - s) + (1-al)*wx ;  s = (u - 1 > 0) ? 1 : 0.
// Output: spikes [B,T,H] f32 (binary). fp32 end-to-end (absmax must be 0 on
// a binary output; R0 confirmed fp32 reorder does not flip any spike).

#define ALPHA_LO_F ((float)0.8187307530779818)   // exp(-1/5)
#define ALPHA_HI_F ((float)0.9607894391523232)   // exp(-1/25)

// ---------------------------------------------------------------------------
// Kernel 1: fp32 "NT" GEMM  C[m,n] = sum_k A[m,k] * B[n,k]   (unchanged R0)
// ---------------------------------------------------------------------------
#define BM 64
#define BN 64
#define BK 16
__global__ __launch_bounds__(256) void gemm_nt_f32(
    const float* __restrict__ A,   // [M, K]
    const float* __restrict__ B,   // [N, K]
    float* __restrict__ C,         // [M, N]
    int M, int N, int K)
{
    __shared__ float As[BK][BM];   // As[k][m]
    __shared__ float Bs[BK][BN];   // Bs[k][n]

    const int tid = threadIdx.x;
    const int tm  = tid >> 4;
    const int tn  = tid & 15;
    const int m0  = blockIdx.y * BM;
    const int n0  = blockIdx.x * BN;

    const int lr = tid >> 2;           // 0..63 : tile row
    const int lk = (tid & 3) * 4;      // 0,4,8,12 : tile k offset

    float acc[4][4] = {};

    const float* Arow = A + (size_t)(m0 + lr) * K + lk;
    const float* Brow = B + (size_t)(n0 + lr) * K + lk;

    for (int k0 = 0; k0 < K; k0 += BK) {
        float4 av = *(const float4*)(Arow + k0);
        float4 bv = *(const float4*)(Brow + k0);
        As[lk + 0][lr] = av.x;  As[lk + 1][lr] = av.y;
        As[lk + 2][lr] = av.z;  As[lk + 3][lr] = av.w;
        Bs[lk + 0][lr] = bv.x;  Bs[lk + 1][lr] = bv.y;
        Bs[lk + 2][lr] = bv.z;  Bs[lk + 3][lr] = bv.w;
        __syncthreads();

        #pragma unroll
        for (int k = 0; k < BK; ++k) {
            float a[4], b[4];
            #pragma unroll
            for (int i = 0; i < 4; ++i) a[i] = As[k][tm * 4 + i];
            #pragma unroll
            for (int j = 0; j < 4; ++j) b[j] = Bs[k][tn * 4 + j];
            #pragma unroll
            for (int i = 0; i < 4; ++i)
                #pragma unroll
                for (int j = 0; j < 4; ++j)
                    acc[i][j] += a[i] * b[j];
        }
        __syncthreads();
    }

    #pragma unroll
    for (int i = 0; i < 4; ++i) {
        float4 v;
        v.x = acc[i][0]; v.y = acc[i][1]; v.z = acc[i][2]; v.w = acc[i][3];
        *(float4*)(C + (size_t)(m0 + tm * 4 + i) * N + n0 + tn * 4) = v;
    }
}

// ---------------------------------------------------------------------------
// Kernel 2: LIF scan, software-pipelined.
// One thread per (b,h) sequence. Depth-16 batched loads, double-buffered:
// issue the 16 loads of batch k+1, then compute+store batch k. This gives
// ~32 outstanding HBM loads/thread-pipeline vs ~1 in R0 (which was pure
// latency-bound: ~1200 cyc/step). 64-thread blocks -> 512 blocks so all
// 256 CUs get work (R0's 128 blocks left half the chip idle).
// ---------------------------------------------------------------------------
#define PF 16
__global__ __launch_bounds__(64) void lif_scan(
    float* __restrict__ buf,            // [B, T, H]: in = Wx, out = spikes
    const float* __restrict__ alpha,    // [H]
    const float* __restrict__ u0,       // [B, H]
    const float* __restrict__ s0,       // [B, H]
    int B, int T, int H)
{
    const int h = blockIdx.x * blockDim.x + threadIdx.x;
    const int b = blockIdx.y;
    if (h >= H) return;

    float al = alpha[h];
    al = fminf(fmaxf(al, ALPHA_LO_F), ALPHA_HI_F);
    const float one_m_al = 1.0f - al;

    float u = u0[(size_t)b * H + h];
    float s = s0[(size_t)b * H + h];

    const size_t sH = (size_t)H;
    size_t idx = (size_t)b * T * H + h;

    float cur[PF], nxt[PF];
    #pragma unroll
    for (int j = 0; j < PF; ++j) cur[j] = buf[idx + (size_t)j * sH];

    for (int t0 = 0; t0 < T; t0 += PF) {
        const size_t nidx = idx + (size_t)PF * sH;
        if (t0 + PF < T) {
            #pragma unroll
            for (int j = 0; j < PF; ++j) nxt[j] = buf[nidx + (size_t)j * sH];
        }
        #pragma unroll
        for (int j = 0; j < PF; ++j) {
            u = al * (u - s) + one_m_al * cur[j];
            s = (u - 1.0f > 0.0f) ? 1.0f : 0.0f;
            cur[j] = s;
        }
        #pragma unroll
        for (int j = 0; j < PF; ++j) buf[idx + (size_t)j * sH] = cur[j];
        #pragma unroll
        for (int j = 0; j < PF; ++j) cur[j] = nxt[j];
        idx = nidx;
    }
}

extern "C" void kernel_launch(void* const* d_in, const int* in_sizes, int n_in,
                              void* d_out, int out_size, void* d_ws, size_t ws_size,
                              hipStream_t stream) {
    const float* x     = (const float*)d_in[0];   // [B, T, I]
    const float* W     = (const float*)d_in[1];   // [H, I]
    const float* alpha = (const float*)d_in[2];   // [H]
    const float* u0    = (const float*)d_in[3];   // [B, H]
    const float* s0    = (const float*)d_in[4];   // [B, H]
    float* out = (float*)d_out;                   // [B, T, H]

    const int H = in_sizes[2];
    const int I = in_sizes[1] / H;
    const int B = in_sizes[3] / H;
    const int T = in_sizes[0] / (B * I);
    const int M = B * T;

    // 1) Wx -> d_out (exactly [B,T,H] f32; reused in-place by the scan)
    dim3 grid1(H / BN, M / BM);
    gemm_nt_f32<<<grid1, 256, 0, stream>>>(x, W, out, M, H, I);

    // 2) scan over T, in-place
    dim3 grid2((H + 63) / 64, B);
    lif_scan<<<grid2, 64, 0, stream>>>(out, alpha, u0, s0, B, T, H);
}

// Round 3
// 617.644 us; speedup vs baseline: 1.6050x; 1.2496x over previous
//
#include <hip/hip_runtime.h>
#include <hip/hip_bf16.h>

// LIF layer: Wx = x @ W^T  (x:[B,T,I] f32, W:[H,I] f32), then sequential scan
// over T:  u = al*(u - s) + (1-al)*wx ;  s = (u - 1 > 0) ? 1 : 0.
// fp32 end-to-end: output is binary, any spike flip = absmax 1.0.
// R0/R1 verified absmax == 0.0 with sequential-k fma accumulation.

#define ALPHA_LO_F ((float)0.8187307530779818)   // exp(-1/5)
#define ALPHA_HI_F ((float)0.9607894391523232)   // exp(-1/25)

typedef float v2f __attribute__((ext_vector_type(2)));

// ---------------------------------------------------------------------------
// Kernel 1: fp32 NT GEMM, 128x128 tile, BK=16, 256 threads, 8x8 acc/thread.
// Accumulate in float2 vectors -> v_pk_fma_f32 (packed fp32, 2x scalar issue).
// LDS layout As[k][m], Bs[k][n]: scatter writes are 2-way bank aliased (free
// per m136); A reads broadcast conflict-free; B b128 reads 4-way (1.58x,
// accepted -- overlapped with VALU across waves).
// M=65536, N=512, K=512 all divide tile dims exactly.
// ---------------------------------------------------------------------------
#define TM 128
#define TN 128
#define TK 16
__global__ __launch_bounds__(256) void gemm_nt_f32(
    const float* __restrict__ A,   // [M, K]
    const float* __restrict__ B,   // [N, K]
    float* __restrict__ C,         // [M, N]
    int M, int N, int K)
{
    __shared__ float As[TK][TM];
    __shared__ float Bs[TK][TN];

    const int tid = threadIdx.x;
    const int m0  = blockIdx.y * TM;
    const int n0  = blockIdx.x * TN;

    // staging map: row = tid>>1 (0..127), kq = (tid&1)*8; two float4 per tile
    const int lrow = tid >> 1;
    const int lkq  = (tid & 1) * 8;

    // compute map: 16x16 threads, 8 rows x 8 cols each
    const int tm = tid >> 4;     // 0..15
    const int tn = tid & 15;     // 0..15

    v2f acc[8][4] = {};

    const float* Arow = A + (size_t)(m0 + lrow) * K + lkq;
    const float* Brow = B + (size_t)(n0 + lrow) * K + lkq;

    for (int k0 = 0; k0 < K; k0 += TK) {
        float4 av0 = *(const float4*)(Arow + k0);
        float4 av1 = *(const float4*)(Arow + k0 + 4);
        float4 bv0 = *(const float4*)(Brow + k0);
        float4 bv1 = *(const float4*)(Brow + k0 + 4);
        As[lkq + 0][lrow] = av0.x;  As[lkq + 1][lrow] = av0.y;
        As[lkq + 2][lrow] = av0.z;  As[lkq + 3][lrow] = av0.w;
        As[lkq + 4][lrow] = av1.x;  As[lkq + 5][lrow] = av1.y;
        As[lkq + 6][lrow] = av1.z;  As[lkq + 7][lrow] = av1.w;
        Bs[lkq + 0][lrow] = bv0.x;  Bs[lkq + 1][lrow] = bv0.y;
        Bs[lkq + 2][lrow] = bv0.z;  Bs[lkq + 3][lrow] = bv0.w;
        Bs[lkq + 4][lrow] = bv1.x;  Bs[lkq + 5][lrow] = bv1.y;
        Bs[lkq + 6][lrow] = bv1.z;  Bs[lkq + 7][lrow] = bv1.w;
        __syncthreads();

        #pragma unroll
        for (int k = 0; k < TK; ++k) {
            const float* Ak = &As[k][tm * 8];
            const float* Bk = &Bs[k][tn * 8];
            float4 a0 = *(const float4*)(Ak);
            float4 a1 = *(const float4*)(Ak + 4);
            float4 b0 = *(const float4*)(Bk);
            float4 b1 = *(const float4*)(Bk + 4);
            v2f bb[4];
            bb[0] = (v2f){b0.x, b0.y};  bb[1] = (v2f){b0.z, b0.w};
            bb[2] = (v2f){b1.x, b1.y};  bb[3] = (v2f){b1.z, b1.w};
            float a[8] = {a0.x, a0.y, a0.z, a0.w, a1.x, a1.y, a1.z, a1.w};
            #pragma unroll
            for (int i = 0; i < 8; ++i) {
                v2f ai = (v2f){a[i], a[i]};
                #pragma unroll
                for (int jv = 0; jv < 4; ++jv)
                    acc[i][jv] = __builtin_elementwise_fma(ai, bb[jv], acc[i][jv]);
            }
        }
        __syncthreads();
    }

    #pragma unroll
    for (int i = 0; i < 8; ++i) {
        float* Crow = C + (size_t)(m0 + tm * 8 + i) * N + n0 + tn * 8;
        float4 v0, v1;
        v0.x = acc[i][0].x; v0.y = acc[i][0].y; v0.z = acc[i][1].x; v0.w = acc[i][1].y;
        v1.x = acc[i][2].x; v1.y = acc[i][2].y; v1.z = acc[i][3].x; v1.w = acc[i][3].y;
        *(float4*)(Crow)     = v0;
        *(float4*)(Crow + 4) = v1;
    }
}

// ---------------------------------------------------------------------------
// Kernel 2: LIF scan, software-pipelined, PF=32.
// Parallelism is capped at 512 waves (one thread per (b,h)); the limiter is
// total in-flight bytes: 512 waves * PF * 256 B. PF=16 -> 2 MB (1.2 TB/s
// measured); PF=32 -> 4 MB, target ~2.5-3 TB/s.
// ---------------------------------------------------------------------------
#define PF 32
__global__ __launch_bounds__(64) void lif_scan(
    float* __restrict__ buf,            // [B, T, H]: in = Wx, out = spikes
    const float* __restrict__ alpha,    // [H]
    const float* __restrict__ u0,       // [B, H]
    const float* __restrict__ s0,       // [B, H]
    int B, int T, int H)
{
    const int h = blockIdx.x * blockDim.x + threadIdx.x;
    const int b = blockIdx.y;
    if (h >= H) return;

    float al = alpha[h];
    al = fminf(fmaxf(al, ALPHA_LO_F), ALPHA_HI_F);
    const float one_m_al = 1.0f - al;

    float u = u0[(size_t)b * H + h];
    float s = s0[(size_t)b * H + h];

    const size_t sH = (size_t)H;
    size_t idx = (size_t)b * T * H + h;

    float cur[PF], nxt[PF];
    #pragma unroll
    for (int j = 0; j < PF; ++j) cur[j] = buf[idx + (size_t)j * sH];

    for (int t0 = 0; t0 < T; t0 += PF) {
        const size_t nidx = idx + (size_t)PF * sH;
        if (t0 + PF < T) {
            #pragma unroll
            for (int j = 0; j < PF; ++j) nxt[j] = buf[nidx + (size_t)j * sH];
        }
        #pragma unroll
        for (int j = 0; j < PF; ++j) {
            u = al * (u - s) + one_m_al * cur[j];
            s = (u - 1.0f > 0.0f) ? 1.0f : 0.0f;
            cur[j] = s;
        }
        #pragma unroll
        for (int j = 0; j < PF; ++j) buf[idx + (size_t)j * sH] = cur[j];
        #pragma unroll
        for (int j = 0; j < PF; ++j) cur[j] = nxt[j];
        idx = nidx;
    }
}

extern "C" void kernel_launch(void* const* d_in, const int* in_sizes, int n_in,
                              void* d_out, int out_size, void* d_ws, size_t ws_size,
                              hipStream_t stream) {
    const float* x     = (const float*)d_in[0];   // [B, T, I]
    const float* W     = (const float*)d_in[1];   // [H, I]
    const float* alpha = (const float*)d_in[2];   // [H]
    const float* u0    = (const float*)d_in[3];   // [B, H]
    const float* s0    = (const float*)d_in[4];   // [B, H]
    float* out = (float*)d_out;                   // [B, T, H]

    const int H = in_sizes[2];
    const int I = in_sizes[1] / H;
    const int B = in_sizes[3] / H;
    const int T = in_sizes[0] / (B * I);
    const int M = B * T;

    // 1) Wx -> d_out (exactly [B,T,H] f32; reused in-place by the scan)
    dim3 grid1(H / TN, M / TM);
    gemm_nt_f32<<<grid1, 256, 0, stream>>>(x, W, out, M, H, I);

    // 2) scan over T, in-place
    dim3 grid2((H + 63) / 64, B);
    lif_scan<<<grid2, 64, 0, stream>>>(out, alpha, u0, s0, B, T, H);
}